// Round 12
// baseline (217.840 us; speedup 1.0000x reference)
//
#include <hip/hip_runtime.h>
#include <hip/hip_bf16.h>

// GDGCN: out[b,c,m,t] = sum_n softmax_row(relu(t1 nv2^T))[n,m] * x[b,c,n,t]
// t1 = nv1 @ (sum_d tv[d] k[d,:,:]);  N=8192, D=32, cols = B*C*T = 192.
// R12: k_mega keeps R11's barrier-dbuf frame (64-m blocks, 4 waves, 8
// chunks) but the ACC phase uses 32x32x16 MFMAs: wave = 3 col-pairs x 1
// msub(32 m) x 4 ksteps = 12 MFMAs with only 4 E b128 LDS reads per stage
// (was 8) -> per-CU LDS burst halves (the shared resource pinning all
// prior variants at ~72 us). y b128 reads double (L2 has headroom). The
// 32x32 B-frag-from-Et[m][n] pattern is correctness-proven by R10's
// consumer. t1 gen operands prefetched a full stage ahead.

#define NN 8192
#define DD 32
#define TT 12
#define NSPLIT 8
#define CHUNK 1024
#define ESTR 72  // Et row stride (ushort): b64 write 4 slots, b128 read 8 slots = data min

typedef __attribute__((ext_vector_type(8))) short bf16x8;
typedef __attribute__((ext_vector_type(4))) short bf16x4;
typedef __attribute__((ext_vector_type(4))) float f32x4;
typedef __attribute__((ext_vector_type(16))) float f32x16;

static __device__ __forceinline__ unsigned short f2bf(float f) {
  unsigned int u = __float_as_uint(f);
  u = (u + 0x7FFFu + ((u >> 16) & 1u)) >> 16;  // RNE bf16
  return (unsigned short)u;
}

static __device__ __forceinline__ float fexp2(float x) {
#if __has_builtin(__builtin_amdgcn_exp2f)
  return __builtin_amdgcn_exp2f(x);
#else
  return __builtin_exp2f(x);
#endif
}

// ---- fused: core = tv.k ; t1 = (nv1@core)*log2e (bf16) ; nv2 -> bf16 ; sums=0
__global__ __launch_bounds__(256) void k_prep(const float* __restrict__ nv1,
                                              const float* __restrict__ nv2,
                                              const float* __restrict__ timevec,
                                              const float* __restrict__ kk,
                                              const int* __restrict__ tind,
                                              unsigned short* __restrict__ t1b,
                                              unsigned short* __restrict__ nv2b,
                                              float* __restrict__ sums) {
  __shared__ float cs[1024];
  const int tid = threadIdx.x;
  if (tid < 128) sums[blockIdx.x * 128 + tid] = 0.f;
  const float* tv = timevec + (size_t)tind[0] * DD;
  for (int idx = tid; idx < 1024; idx += 256) {
    float acc = 0.f;
#pragma unroll
    for (int d = 0; d < DD; ++d) acc += tv[d] * kk[d * 1024 + idx];
    cs[idx] = acc;
  }
  __syncthreads();
  const int nbase = blockIdx.x * 128;
  const int f = tid & 31, sub = tid >> 5;
#pragma unroll 4
  for (int it = 0; it < 16; ++it) {
    const int n = nbase + it * 8 + sub;
    const float* nr = nv1 + (size_t)n * DD;
    float acc = 0.f;
#pragma unroll
    for (int e = 0; e < DD; ++e) acc += nr[e] * cs[e * DD + f];
    t1b[(size_t)n * DD + f] = f2bf(acc * 1.4426950408889634f);  // fold log2(e)
  }
#pragma unroll 4
  for (int it = 0; it < 16; ++it) {
    const int idx = nbase * DD + it * 256 + tid;
    nv2b[idx] = f2bf(nv2[idx]);
  }
}

// ---- sums[n] += sum_m exp2(relu(t1[n].nv2[m]))  grid (128 n, 8 m-chunks) ----
__global__ __launch_bounds__(256) void k_stats(const unsigned short* __restrict__ t1b,
                                               const unsigned short* __restrict__ nv2b,
                                               float* __restrict__ sums) {
  const int tid = threadIdx.x;
  const int w = tid >> 6, lane = tid & 63, q = lane >> 4, i16 = lane & 15;
  const int nbase = blockIdx.x * 64 + w * 16;
  bf16x8 a = *(const bf16x8*)(t1b + (size_t)(nbase + i16) * DD + q * 8);
  const f32x4 z4 = {0.f, 0.f, 0.f, 0.f};
  float s[4] = {0.f, 0.f, 0.f, 0.f};
  const int m0 = blockIdx.y * 1024;
  for (int mt = m0; mt < m0 + 1024; mt += 64) {
#pragma unroll
    for (int u = 0; u < 4; ++u) {
      bf16x8 b = *(const bf16x8*)(nv2b + (size_t)(mt + u * 16 + i16) * DD + q * 8);
      f32x4 d = __builtin_amdgcn_mfma_f32_16x16x32_bf16(a, b, z4, 0, 0, 0);
#pragma unroll
      for (int r = 0; r < 4; ++r) s[r] += fexp2(fmaxf(d[r], 0.f));
    }
  }
#pragma unroll
  for (int r = 0; r < 4; ++r)
    for (int off = 1; off < 16; off <<= 1) s[r] += __shfl_xor(s[r], off, 64);
  if (i16 == 0) {
#pragma unroll
    for (int r = 0; r < 4; ++r) atomicAdd(&sums[nbase + q * 4 + r], s[r]);
  }
}

// ---- yT[col][n] = bf16(x[bc][n][t] / sums[n]) via LDS transpose ----
__global__ __launch_bounds__(256) void k_y(const float* __restrict__ x,
                                           const float* __restrict__ sums,
                                           unsigned short* __restrict__ yT) {
  __shared__ float xs[3072];
  const int tid = threadIdx.x;
  const int n0 = blockIdx.x * 256;
  const int bc = blockIdx.y;
  const float* xp = x + (size_t)bc * NN * TT + (size_t)n0 * TT;
#pragma unroll
  for (int j = 0; j < 12; ++j) xs[j * 256 + tid] = xp[j * 256 + tid];
  __syncthreads();
  const float rinv = 1.0f / sums[n0 + tid];
#pragma unroll
  for (int t = 0; t < 12; ++t)
    yT[(size_t)(bc * TT + t) * NN + n0 + tid] = f2bf(xs[tid * 12 + t] * rinv);
}

// ---- k_mega: part[nc][col][m] = sum_{n in chunk} E[n][m] * y[col][n] ----
// grid (128 m-blocks of 64, 8 chunks of 1024 n); 256 thr = 4 waves.
// Stage = 64 n, double-buffered Et[2][64 m][ESTR n]. Gen (16x16, R11
// verbatim): wave w -> E rows [w*16,+16) x 64 n; t1 operands prefetched a
// full stage ahead (atc/atn). Acc (32x32x16): wave (wc=w&1, wm=w>>1) ->
// col-pairs [wc*3,+3) x m rows [wm*32,+32) x 4 ksteps = 12 MFMAs, only 4
// Et b128 reads/stage. One barrier/stage.
__global__ __launch_bounds__(256, 3) void k_mega(const unsigned short* __restrict__ t1b,
                                                 const unsigned short* __restrict__ nv2b,
                                                 const unsigned short* __restrict__ yT,
                                                 float* __restrict__ part) {
  const int tid = threadIdx.x;
  const int w = tid >> 6, lane = tid & 63, q = lane >> 4, i16 = lane & 15;
  const int h = lane >> 5, l31 = lane & 31;
  const int wc = w & 1, wm = w >> 1;
  const int mb = blockIdx.x * 64;
  const int nt0 = blockIdx.y * CHUNK;

  __shared__ unsigned short Ew[2][64][ESTR];  // 18432 B

  // gen B-frag (loop-invariant): B[d][m=i16] = nv2[mb + w*16 + i16][d]
  const bf16x8 bg = *(const bf16x8*)(nv2b + (size_t)(mb + w * 16 + i16) * DD + q * 8);
  const int rowm = w * 16 + i16;

  const f32x4 z4 = {0.f, 0.f, 0.f, 0.f};
  f32x16 acc[3];
#pragma unroll
  for (int c = 0; c < 3; ++c)
#pragma unroll
    for (int r = 0; r < 16; ++r) acc[c][r] = 0.f;

  // ---- prologue: generate stage 0 (64 n) into buf 0; load t1 for stage-0 gen
#pragma unroll
  for (int s = 0; s < 4; ++s) {
    bf16x8 at = *(const bf16x8*)(t1b + (size_t)(nt0 + s * 16 + i16) * DD + q * 8);
    f32x4 d = __builtin_amdgcn_mfma_f32_16x16x32_bf16(at, bg, z4, 0, 0, 0);
    bf16x4 e;
#pragma unroll
    for (int r = 0; r < 4; ++r) e[r] = (short)f2bf(fexp2(fmaxf(d[r], 0.f)));
    *(bf16x4*)&Ew[0][rowm][s * 16 + q * 4] = e;
  }
  bf16x8 atc[4];  // t1 rows for the gen performed during stage st (targets stage st+1)
#pragma unroll
  for (int s = 0; s < 4; ++s)
    atc[s] = *(const bf16x8*)(t1b + (size_t)(nt0 + 64 + s * 16 + i16) * DD + q * 8);
  __syncthreads();

  int p = 0;
  for (int st = 0; st < 16; ++st, p ^= 1) {
    const int nt = nt0 + st * 64;
    const bool more = (st < 15);

    // 1. issue t1 loads for NEXT stage's gen (full stage of latency slack)
    bf16x8 atn[4];
    if (st < 14) {
#pragma unroll
      for (int s = 0; s < 4; ++s)
        atn[s] = *(const bf16x8*)(t1b + (size_t)(nt + 128 + s * 16 + i16) * DD + q * 8);
    }

    // 2. y A-frags for this stage (12 b128 from L2): A[col=l31][k=h*8+j]
    bf16x8 yf[3][4];
#pragma unroll
    for (int c = 0; c < 3; ++c) {
      const unsigned short* yp = yT + (size_t)((wc * 3 + c) * 32 + l31) * NN + nt + h * 8;
#pragma unroll
      for (int ks = 0; ks < 4; ++ks) yf[c][ks] = *(const bf16x8*)(yp + ks * 16);
    }

    // 3. E B-frags (4 b128 LDS): B[k=h*8+j][m=l31] = Ew[p][wm*32+l31][ks*16+h*8+j]
    bf16x8 ef[4];
#pragma unroll
    for (int ks = 0; ks < 4; ++ks)
      ef[ks] = *(const bf16x8*)&Ew[p][wm * 32 + l31][ks * 16 + h * 8];

    // 4. gen MFMAs for stage st+1 (atc prefetched last stage -> no L2 stall)
    f32x4 dg[4];
    if (more) {
#pragma unroll
      for (int s = 0; s < 4; ++s)
        dg[s] = __builtin_amdgcn_mfma_f32_16x16x32_bf16(atc[s], bg, z4, 0, 0, 0);
      // 5. exp2 + pack + store into buf p^1 (VALU overlaps y/LDS latency)
#pragma unroll
      for (int s = 0; s < 4; ++s) {
        bf16x4 e;
#pragma unroll
        for (int r = 0; r < 4; ++r) e[r] = (short)f2bf(fexp2(fmaxf(dg[s][r], 0.f)));
        *(bf16x4*)&Ew[p ^ 1][rowm][s * 16 + q * 4] = e;
      }
    }

    // 6. acc: 12 x 32x32x16 MFMAs (3 independent chains)
#pragma unroll
    for (int ks = 0; ks < 4; ++ks)
#pragma unroll
      for (int c = 0; c < 3; ++c)
        acc[c] = __builtin_amdgcn_mfma_f32_32x32x16_bf16(yf[c][ks], ef[ks], acc[c], 0, 0, 0);

#pragma unroll
    for (int s = 0; s < 4; ++s) atc[s] = atn[s];
    __syncthreads();  // buf p reads done; buf p^1 writes visible
  }

  // epilogue: acc[c] reg r -> col = (wc*3+c)*32 + (r&3) + 8*(r>>2) + 4*h,
  //           m = mb + wm*32 + l31  (coalesced over l31)
  float* pp = part + (size_t)blockIdx.y * 192 * NN;
#pragma unroll
  for (int c = 0; c < 3; ++c)
#pragma unroll
    for (int r = 0; r < 16; ++r) {
      const int col = (wc * 3 + c) * 32 + (r & 3) + 8 * (r >> 2) + 4 * h;
      pp[(size_t)col * NN + mb + wm * 32 + l31] = acc[c][r];
    }
}

// ---- reduce NSPLIT partials + transpose to out[bc][m][t] ----
__global__ __launch_bounds__(256) void k_reduce(const float* __restrict__ part,
                                                float* __restrict__ out) {
  __shared__ float os[3072];
  const int tid = threadIdx.x;
  const int m0 = blockIdx.x * 256;
  const int bc = blockIdx.y;
#pragma unroll
  for (int t = 0; t < 12; ++t) {
    const int col = bc * TT + t;
    float s = 0.f;
#pragma unroll
    for (int nc = 0; nc < NSPLIT; ++nc)
      s += part[((size_t)nc * 192 + col) * NN + m0 + tid];
    os[tid * 12 + t] = s;
  }
  __syncthreads();
  float* op = out + (size_t)bc * NN * TT + (size_t)m0 * TT;
#pragma unroll
  for (int j = 0; j < 12; ++j) op[j * 256 + tid] = os[j * 256 + tid];
}

extern "C" void kernel_launch(void* const* d_in, const int* in_sizes, int n_in,
                              void* d_out, int out_size, void* d_ws, size_t ws_size,
                              hipStream_t stream) {
  const float* x = (const float*)d_in[0];
  const float* nv1 = (const float*)d_in[1];
  const float* nv2 = (const float*)d_in[2];
  const float* tv = (const float*)d_in[3];
  const float* kk = (const float*)d_in[4];
  const int* tind = (const int*)d_in[5];
  float* out = (float*)d_out;

  char* ws = (char*)d_ws;
  unsigned short* t1b  = (unsigned short*)(ws);            //  524288 B
  unsigned short* nv2b = (unsigned short*)(ws + 524288);   //  524288 B
  float* sums          = (float*)(ws + 1048576);           //   32768 B
  unsigned short* yT   = (unsigned short*)(ws + 1081344);  // 3145728 B -> 4227072
  float* part          = (float*)(ws + 4227072);           // 50331648 B -> 54558720

  k_prep<<<64, 256, 0, stream>>>(nv1, nv2, tv, kk, tind, t1b, nv2b, sums);
  k_stats<<<dim3(128, 8), 256, 0, stream>>>(t1b, nv2b, sums);
  k_y<<<dim3(32, 16), 256, 0, stream>>>(x, sums, yT);
  k_mega<<<dim3(128, NSPLIT), 256, 0, stream>>>(t1b, nv2b, yT, part);
  k_reduce<<<dim3(32, 16), 256, 0, stream>>>(part, out);
}

// Round 13
// 188.728 us; speedup vs baseline: 1.1543x; 1.1543x over previous
//
#include <hip/hip_runtime.h>
#include <hip/hip_bf16.h>

// GDGCN: out[b,c,m,t] = sum_n softmax_row(relu(t1 nv2^T))[n,m] * x[b,c,n,t]
// t1 = nv1 @ (sum_d tv[d] k[d,:,:]);  N=8192, D=32, cols = B*C*T = 192.
// R13: k_mega = ONE barrier per 1024-n chunk. The whole E chunk (64 m x
// 1024 n bf16, stride 1048 = bank-optimal & 16B-aligned) lives in 131 KB
// LDS (CDNA4 has 160 KB). Phase 1: each wave privately generates its 16
// m-rows x 1024 n (64 MFMAs + 256 exp2, no sync). One __syncthreads.
// Phase 2: barrier-free streaming acc GEMM (12 independent MFMA chains,
// y from L2, E b128 from LDS). Kills the per-64n lockstep that pinned
// R5/6/8/11/12 at ~72 us. Gated on MaxSharedMemoryPerBlock; fallback =
// R11 k_mega verbatim.

#define NN 8192
#define DD 32
#define TT 12
#define NSPLIT 8
#define CHUNK 1024
#define ESTR 72     // fallback Et row stride
#define ESTR2 1048  // big-LDS row stride (ushort): b128 8 slots, b64 4 = data-min
#define MEGA_LDS (64 * ESTR2 * 2)  // 134144 B

typedef __attribute__((ext_vector_type(8))) short bf16x8;
typedef __attribute__((ext_vector_type(4))) short bf16x4;
typedef __attribute__((ext_vector_type(4))) float f32x4;

static __device__ __forceinline__ unsigned short f2bf(float f) {
  unsigned int u = __float_as_uint(f);
  u = (u + 0x7FFFu + ((u >> 16) & 1u)) >> 16;  // RNE bf16
  return (unsigned short)u;
}

static __device__ __forceinline__ float fexp2(float x) {
#if __has_builtin(__builtin_amdgcn_exp2f)
  return __builtin_amdgcn_exp2f(x);
#else
  return __builtin_exp2f(x);
#endif
}

// ---- fused: core = tv.k ; t1 = (nv1@core)*log2e (bf16) ; nv2 -> bf16 ; sums=0
__global__ __launch_bounds__(256) void k_prep(const float* __restrict__ nv1,
                                              const float* __restrict__ nv2,
                                              const float* __restrict__ timevec,
                                              const float* __restrict__ kk,
                                              const int* __restrict__ tind,
                                              unsigned short* __restrict__ t1b,
                                              unsigned short* __restrict__ nv2b,
                                              float* __restrict__ sums) {
  __shared__ float cs[1024];
  const int tid = threadIdx.x;
  if (tid < 128) sums[blockIdx.x * 128 + tid] = 0.f;
  const float* tv = timevec + (size_t)tind[0] * DD;
  for (int idx = tid; idx < 1024; idx += 256) {
    float acc = 0.f;
#pragma unroll
    for (int d = 0; d < DD; ++d) acc += tv[d] * kk[d * 1024 + idx];
    cs[idx] = acc;
  }
  __syncthreads();
  const int nbase = blockIdx.x * 128;
  const int f = tid & 31, sub = tid >> 5;
#pragma unroll 4
  for (int it = 0; it < 16; ++it) {
    const int n = nbase + it * 8 + sub;
    const float* nr = nv1 + (size_t)n * DD;
    float acc = 0.f;
#pragma unroll
    for (int e = 0; e < DD; ++e) acc += nr[e] * cs[e * DD + f];
    t1b[(size_t)n * DD + f] = f2bf(acc * 1.4426950408889634f);  // fold log2(e)
  }
#pragma unroll 4
  for (int it = 0; it < 16; ++it) {
    const int idx = nbase * DD + it * 256 + tid;
    nv2b[idx] = f2bf(nv2[idx]);
  }
}

// ---- sums[n] += sum_m exp2(relu(t1[n].nv2[m]))  grid (128 n, 8 m-chunks) ----
__global__ __launch_bounds__(256) void k_stats(const unsigned short* __restrict__ t1b,
                                               const unsigned short* __restrict__ nv2b,
                                               float* __restrict__ sums) {
  const int tid = threadIdx.x;
  const int w = tid >> 6, lane = tid & 63, q = lane >> 4, i16 = lane & 15;
  const int nbase = blockIdx.x * 64 + w * 16;
  bf16x8 a = *(const bf16x8*)(t1b + (size_t)(nbase + i16) * DD + q * 8);
  const f32x4 z4 = {0.f, 0.f, 0.f, 0.f};
  float s[4] = {0.f, 0.f, 0.f, 0.f};
  const int m0 = blockIdx.y * 1024;
  for (int mt = m0; mt < m0 + 1024; mt += 64) {
#pragma unroll
    for (int u = 0; u < 4; ++u) {
      bf16x8 b = *(const bf16x8*)(nv2b + (size_t)(mt + u * 16 + i16) * DD + q * 8);
      f32x4 d = __builtin_amdgcn_mfma_f32_16x16x32_bf16(a, b, z4, 0, 0, 0);
#pragma unroll
      for (int r = 0; r < 4; ++r) s[r] += fexp2(fmaxf(d[r], 0.f));
    }
  }
#pragma unroll
  for (int r = 0; r < 4; ++r)
    for (int off = 1; off < 16; off <<= 1) s[r] += __shfl_xor(s[r], off, 64);
  if (i16 == 0) {
#pragma unroll
    for (int r = 0; r < 4; ++r) atomicAdd(&sums[nbase + q * 4 + r], s[r]);
  }
}

// ---- yT[col][n] = bf16(x[bc][n][t] / sums[n]) via LDS transpose ----
__global__ __launch_bounds__(256) void k_y(const float* __restrict__ x,
                                           const float* __restrict__ sums,
                                           unsigned short* __restrict__ yT) {
  __shared__ float xs[3072];
  const int tid = threadIdx.x;
  const int n0 = blockIdx.x * 256;
  const int bc = blockIdx.y;
  const float* xp = x + (size_t)bc * NN * TT + (size_t)n0 * TT;
#pragma unroll
  for (int j = 0; j < 12; ++j) xs[j * 256 + tid] = xp[j * 256 + tid];
  __syncthreads();
  const float rinv = 1.0f / sums[n0 + tid];
#pragma unroll
  for (int t = 0; t < 12; ++t)
    yT[(size_t)(bc * TT + t) * NN + n0 + tid] = f2bf(xs[tid * 12 + t] * rinv);
}

// ---- k_mega (R13): part[nc][col][m] = sum_{n in chunk} E[n][m] * y[col][n] ----
// grid (128 m-blocks of 64, 8 chunks of 1024 n); 256 thr = 4 waves; 1 block/CU.
// Phase 1 (no sync): wave w -> E rows [w*16,+16) x 1024 n into Et (131 KB).
// ONE barrier. Phase 2 (no sync): wave w -> coltiles [w*3,+3) x 4 msubs,
// 32 half-steps x 12 independent MFMAs; y b128 from L2, E b128 from LDS.
__global__ __launch_bounds__(256, 1) void k_mega(const unsigned short* __restrict__ t1b,
                                                 const unsigned short* __restrict__ nv2b,
                                                 const unsigned short* __restrict__ yT,
                                                 float* __restrict__ part) {
  extern __shared__ unsigned short Et[];  // [64][ESTR2]
  const int tid = threadIdx.x;
  const int w = tid >> 6, lane = tid & 63, q = lane >> 4, i16 = lane & 15;
  const int mb = blockIdx.x * 64;
  const int nt0 = blockIdx.y * CHUNK;
  const f32x4 z4 = {0.f, 0.f, 0.f, 0.f};

  // ---------- phase 1: generate E rows [w*16,+16) x all 1024 n ----------
  {
    const bf16x8 bg = *(const bf16x8*)(nv2b + (size_t)(mb + w * 16 + i16) * DD + q * 8);
    unsigned short* erow = Et + (size_t)(w * 16 + i16) * ESTR2;
    bf16x8 at[4], nx[4];
#pragma unroll
    for (int s = 0; s < 4; ++s)
      at[s] = *(const bf16x8*)(t1b + (size_t)(nt0 + s * 16 + i16) * DD + q * 8);
    for (int g = 0; g < 16; ++g) {
      if (g < 15) {
#pragma unroll
        for (int s = 0; s < 4; ++s)
          nx[s] = *(const bf16x8*)(t1b + (size_t)(nt0 + (g + 1) * 64 + s * 16 + i16) * DD + q * 8);
      }
#pragma unroll
      for (int s = 0; s < 4; ++s) {
        // D[n-local = q*4+r][m-local = i16]; store n-contiguous b64 at row m
        f32x4 d = __builtin_amdgcn_mfma_f32_16x16x32_bf16(at[s], bg, z4, 0, 0, 0);
        bf16x4 e;
#pragma unroll
        for (int r = 0; r < 4; ++r) e[r] = (short)f2bf(fexp2(fmaxf(d[r], 0.f)));
        *(bf16x4*)&erow[g * 64 + s * 16 + q * 4] = e;
      }
#pragma unroll
      for (int s = 0; s < 4; ++s) at[s] = nx[s];
    }
  }
  __syncthreads();  // the ONLY barrier

  // ---------- phase 2: streaming acc, no sync ----------
  f32x4 acc[3][4];
#pragma unroll
  for (int c = 0; c < 3; ++c)
#pragma unroll
    for (int ms = 0; ms < 4; ++ms) acc[c][ms] = (f32x4){0.f, 0.f, 0.f, 0.f};

  const unsigned short* yp[3];
#pragma unroll
  for (int c = 0; c < 3; ++c)
    yp[c] = yT + (size_t)((w * 3 + c) * 16 + i16) * NN + nt0 + q * 8;

#pragma unroll 2
  for (int st = 0; st < 32; ++st) {  // 32 half-steps of 32 n
    const int nb = st * 32;
    bf16x8 yfr[3], efr[4];
#pragma unroll
    for (int c = 0; c < 3; ++c) yfr[c] = *(const bf16x8*)(yp[c] + nb);
#pragma unroll
    for (int ms = 0; ms < 4; ++ms)
      efr[ms] = *(const bf16x8*)&Et[(size_t)(ms * 16 + i16) * ESTR2 + nb + q * 8];
#pragma unroll
    for (int c = 0; c < 3; ++c)
#pragma unroll
      for (int ms = 0; ms < 4; ++ms)
        acc[c][ms] = __builtin_amdgcn_mfma_f32_16x16x32_bf16(yfr[c], efr[ms], acc[c][ms], 0, 0, 0);
  }

  // epilogue: lane holds col = (w*3+c)*16 + q*4 + r, m = mb + ms*16 + i16
  float* pp = part + (size_t)blockIdx.y * 192 * NN;
#pragma unroll
  for (int c = 0; c < 3; ++c)
#pragma unroll
    for (int ms = 0; ms < 4; ++ms) {
      const int colbase = (w * 3 + c) * 16 + q * 4;
      const int m = mb + ms * 16 + i16;
#pragma unroll
      for (int r = 0; r < 4; ++r)
        pp[(size_t)(colbase + r) * NN + m] = acc[c][ms][r];
    }
}

// ---- fallback: R11 k_mega verbatim (72 us, proven) ----
__global__ __launch_bounds__(256, 4) void k_mega_fb(const unsigned short* __restrict__ t1b,
                                                    const unsigned short* __restrict__ nv2b,
                                                    const unsigned short* __restrict__ yT,
                                                    float* __restrict__ part) {
  const int tid = threadIdx.x;
  const int w = tid >> 6, lane = tid & 63, q = lane >> 4, i16 = lane & 15;
  const int mb = blockIdx.x * 64;
  const int nt0 = blockIdx.y * CHUNK;
  __shared__ unsigned short Ew[2][64][ESTR];
  const bf16x8 bg = *(const bf16x8*)(nv2b + (size_t)(mb + w * 16 + i16) * DD + q * 8);
  const int rowm = w * 16 + i16;
  const f32x4 z4 = {0.f, 0.f, 0.f, 0.f};
  f32x4 acc[3][4];
#pragma unroll
  for (int c = 0; c < 3; ++c)
#pragma unroll
    for (int ms = 0; ms < 4; ++ms) acc[c][ms] = (f32x4){0.f, 0.f, 0.f, 0.f};
#pragma unroll
  for (int s = 0; s < 4; ++s) {
    bf16x8 at = *(const bf16x8*)(t1b + (size_t)(nt0 + s * 16 + i16) * DD + q * 8);
    f32x4 d = __builtin_amdgcn_mfma_f32_16x16x32_bf16(at, bg, z4, 0, 0, 0);
    bf16x4 e;
#pragma unroll
    for (int r = 0; r < 4; ++r) e[r] = (short)f2bf(fexp2(fmaxf(d[r], 0.f)));
    *(bf16x4*)&Ew[0][rowm][s * 16 + q * 4] = e;
  }
  __syncthreads();
  int p = 0;
  for (int st = 0; st < 16; ++st, p ^= 1) {
    const int nt = nt0 + st * 64;
    const bool more = (st < 15);
    bf16x8 atn[4];
    if (more) {
#pragma unroll
      for (int s = 0; s < 4; ++s)
        atn[s] = *(const bf16x8*)(t1b + (size_t)(nt + 64 + s * 16 + i16) * DD + q * 8);
    }
    bf16x8 yfr[3], efr[4];
#pragma unroll
    for (int c = 0; c < 3; ++c)
      yfr[c] = *(const bf16x8*)(yT + (size_t)((w * 3 + c) * 16 + i16) * NN + nt + q * 8);
#pragma unroll
    for (int ms = 0; ms < 4; ++ms)
      efr[ms] = *(const bf16x8*)&Ew[p][ms * 16 + i16][q * 8];
    f32x4 d0, d1;
    if (more) {
      d0 = __builtin_amdgcn_mfma_f32_16x16x32_bf16(atn[0], bg, z4, 0, 0, 0);
      d1 = __builtin_amdgcn_mfma_f32_16x16x32_bf16(atn[1], bg, z4, 0, 0, 0);
    }
#pragma unroll
    for (int c = 0; c < 3; ++c)
#pragma unroll
      for (int ms = 0; ms < 4; ++ms)
        acc[c][ms] = __builtin_amdgcn_mfma_f32_16x16x32_bf16(yfr[c], efr[ms], acc[c][ms], 0, 0, 0);
    if (more) {
      bf16x4 e0, e1;
#pragma unroll
      for (int r = 0; r < 4; ++r) {
        e0[r] = (short)f2bf(fexp2(fmaxf(d0[r], 0.f)));
        e1[r] = (short)f2bf(fexp2(fmaxf(d1[r], 0.f)));
      }
      *(bf16x4*)&Ew[p ^ 1][rowm][q * 4] = e0;
      *(bf16x4*)&Ew[p ^ 1][rowm][16 + q * 4] = e1;
      f32x4 d2 = __builtin_amdgcn_mfma_f32_16x16x32_bf16(atn[2], bg, z4, 0, 0, 0);
      f32x4 d3 = __builtin_amdgcn_mfma_f32_16x16x32_bf16(atn[3], bg, z4, 0, 0, 0);
      bf16x4 e2, e3;
#pragma unroll
      for (int r = 0; r < 4; ++r) {
        e2[r] = (short)f2bf(fexp2(fmaxf(d2[r], 0.f)));
        e3[r] = (short)f2bf(fexp2(fmaxf(d3[r], 0.f)));
      }
      *(bf16x4*)&Ew[p ^ 1][rowm][32 + q * 4] = e2;
      *(bf16x4*)&Ew[p ^ 1][rowm][48 + q * 4] = e3;
    }
#pragma unroll
    for (int c = 0; c < 3; ++c)
      yfr[c] = *(const bf16x8*)(yT + (size_t)((w * 3 + c) * 16 + i16) * NN + nt + 32 + q * 8);
#pragma unroll
    for (int ms = 0; ms < 4; ++ms)
      efr[ms] = *(const bf16x8*)&Ew[p][ms * 16 + i16][32 + q * 8];
#pragma unroll
    for (int c = 0; c < 3; ++c)
#pragma unroll
      for (int ms = 0; ms < 4; ++ms)
        acc[c][ms] = __builtin_amdgcn_mfma_f32_16x16x32_bf16(yfr[c], efr[ms], acc[c][ms], 0, 0, 0);
    __syncthreads();
  }
  float* pp = part + (size_t)blockIdx.y * 192 * NN;
#pragma unroll
  for (int c = 0; c < 3; ++c)
#pragma unroll
    for (int ms = 0; ms < 4; ++ms) {
      const int colbase = (w * 3 + c) * 16 + q * 4;
      const int m = mb + ms * 16 + i16;
#pragma unroll
      for (int r = 0; r < 4; ++r)
        pp[(size_t)(colbase + r) * NN + m] = acc[c][ms][r];
    }
}

// ---- reduce NSPLIT partials + transpose to out[bc][m][t] ----
__global__ __launch_bounds__(256) void k_reduce(const float* __restrict__ part,
                                                float* __restrict__ out) {
  __shared__ float os[3072];
  const int tid = threadIdx.x;
  const int m0 = blockIdx.x * 256;
  const int bc = blockIdx.y;
#pragma unroll
  for (int t = 0; t < 12; ++t) {
    const int col = bc * TT + t;
    float s = 0.f;
#pragma unroll
    for (int nc = 0; nc < NSPLIT; ++nc)
      s += part[((size_t)nc * 192 + col) * NN + m0 + tid];
    os[tid * 12 + t] = s;
  }
  __syncthreads();
  float* op = out + (size_t)bc * NN * TT + (size_t)m0 * TT;
#pragma unroll
  for (int j = 0; j < 12; ++j) op[j * 256 + tid] = os[j * 256 + tid];
}

extern "C" void kernel_launch(void* const* d_in, const int* in_sizes, int n_in,
                              void* d_out, int out_size, void* d_ws, size_t ws_size,
                              hipStream_t stream) {
  const float* x = (const float*)d_in[0];
  const float* nv1 = (const float*)d_in[1];
  const float* nv2 = (const float*)d_in[2];
  const float* tv = (const float*)d_in[3];
  const float* kk = (const float*)d_in[4];
  const int* tind = (const int*)d_in[5];
  float* out = (float*)d_out;

  char* ws = (char*)d_ws;
  unsigned short* t1b  = (unsigned short*)(ws);            //  524288 B
  unsigned short* nv2b = (unsigned short*)(ws + 524288);   //  524288 B
  float* sums          = (float*)(ws + 1048576);           //   32768 B
  unsigned short* yT   = (unsigned short*)(ws + 1081344);  // 3145728 B -> 4227072
  float* part          = (float*)(ws + 4227072);           // 50331648 B -> 54558720

  k_prep<<<64, 256, 0, stream>>>(nv1, nv2, tv, kk, tind, t1b, nv2b, sums);
  k_stats<<<dim3(128, 8), 256, 0, stream>>>(t1b, nv2b, sums);
  k_y<<<dim3(32, 16), 256, 0, stream>>>(x, sums, yT);

  int dev = 0;
  (void)hipGetDevice(&dev);
  int maxshm = 0;
  (void)hipDeviceGetAttribute(&maxshm, hipDeviceAttributeMaxSharedMemoryPerBlock, dev);
  (void)hipFuncSetAttribute((const void*)k_mega, hipFuncAttributeMaxDynamicSharedMemorySize,
                            MEGA_LDS);
  if (maxshm >= MEGA_LDS) {
    k_mega<<<dim3(128, NSPLIT), 256, MEGA_LDS, stream>>>(t1b, nv2b, yT, part);
  } else {
    k_mega_fb<<<dim3(128, NSPLIT), 256, 0, stream>>>(t1b, nv2b, yT, part);
  }
  k_reduce<<<dim3(32, 16), 256, 0, stream>>>(part, out);
}